// Round 5
// baseline (999.062 us; speedup 1.0000x reference)
//
#include <hip/hip_runtime.h>
#include <math.h>

#define N_NODES   100000
#define N_EDGES   1600000
#define N_FEAT    64
#define HIDDEN    64
#define BIOPRINT  2048
#define N_GRAPHS  1024
#define N8        (N_NODES * 8)     // floats per feature-slice [8][N][8]

#define SCAN_BLK  1024
#define N_SCAN_BLOCKS ((N_NODES + SCAN_BLK - 1) / SCAN_BLK)   // 98

// ---------------- degree / normalization ----------------

__global__ void k_deg(const int* __restrict__ dst, int* __restrict__ deg, int n) {
    int i = blockIdx.x * blockDim.x + threadIdx.x;
    if (i < n) atomicAdd(&deg[dst[i]], 1);
}

__global__ void k_dinv(const int* __restrict__ deg, float* __restrict__ dinv, int n) {
    int i = blockIdx.x * blockDim.x + threadIdx.x;
    if (i < n) dinv[i] = rsqrtf((float)deg[i] + 1.0f);
}

// ---------------- CSR build ----------------

__global__ __launch_bounds__(SCAN_BLK) void k_scan1(
        const int* __restrict__ deg, int* __restrict__ incl,
        int* __restrict__ bsum, int n) {
    __shared__ int tmp[SCAN_BLK];
    int t = threadIdx.x;
    int i = blockIdx.x * SCAN_BLK + t;
    int v = (i < n) ? deg[i] : 0;
    tmp[t] = v;
    __syncthreads();
    for (int off = 1; off < SCAN_BLK; off <<= 1) {
        int u = (t >= off) ? tmp[t - off] : 0;
        __syncthreads();
        tmp[t] += u;
        __syncthreads();
    }
    if (i < n) incl[i] = tmp[t];
    if (t == SCAN_BLK - 1) bsum[blockIdx.x] = tmp[t];
}

__global__ void k_scan2(int* __restrict__ bsum, int nb) {
    if (threadIdx.x == 0 && blockIdx.x == 0) {
        int run = 0;
        for (int b = 0; b < nb; ++b) { int v = bsum[b]; bsum[b] = run; run += v; }
    }
}

__global__ __launch_bounds__(SCAN_BLK) void k_scan3(
        int* __restrict__ rowptr, const int* __restrict__ deg,
        const int* __restrict__ bsum, int* __restrict__ cursor, int n) {
    int i = blockIdx.x * SCAN_BLK + threadIdx.x;
    if (i < n) {
        int ex = rowptr[i] - deg[i] + bsum[blockIdx.x];
        rowptr[i] = ex;
        cursor[i] = ex;
    }
    if (i == 0) rowptr[n] = N_EDGES;
}

__global__ void k_fill(const int* __restrict__ src, const int* __restrict__ dst,
                       int* __restrict__ cursor, int* __restrict__ col, int n) {
    int e = blockIdx.x * blockDim.x + threadIdx.x;
    if (e < n) {
        int s = src[e], d = dst[e];
        int pos = atomicAdd(&cursor[d], 1);
        col[pos] = s;
    }
}

// ---------------- graph segment boundaries (batch is sorted) ----------------
__global__ void k_gstart(const int* __restrict__ batch, int* __restrict__ gstart) {
    int g = blockIdx.x * blockDim.x + threadIdx.x;
    if (g > N_GRAPHS) return;
    if (g == N_GRAPHS) { gstart[g] = N_NODES; return; }
    int lo = 0, hi = N_NODES;
    while (lo < hi) { int mid = (lo + hi) >> 1; if (batch[mid] < g) lo = mid + 1; else hi = mid; }
    gstart[g] = lo;
}

// ---------------- layer-1 matmul: hw1' = (x @ W1) * dinv, sliced store ----------------
__global__ __launch_bounds__(256) void k_mm(
        const float* __restrict__ h, const float* __restrict__ W,
        const float* __restrict__ dinv, float* __restrict__ hw8) {
    __shared__ float sW[64 * 64];
    __shared__ float sH[4 * 64];
    int t = threadIdx.x;
    const float4* W4 = (const float4*)W;
    float4* sW4 = (float4*)sW;
    for (int i = t; i < 1024; i += 256) sW4[i] = W4[i];
    int row0 = blockIdx.x * 4;
    int r = t >> 6, j = t & 63;
    sH[r * 64 + j] = h[(row0 + r) * 64 + j];
    __syncthreads();
    int i = row0 + r;
    float sum = 0.0f;
#pragma unroll
    for (int k = 0; k < 64; ++k) sum = fmaf(sH[r * 64 + k], sW[k * 64 + j], sum);
    hw8[(size_t)(j >> 3) * N8 + i * 8 + (j & 7)] = sum * dinv[i];
}

// ---------------- sliced gather: agg8[p][i] = sum_e hw8[p][col[e]] ----------------
// p = blockIdx&7 -> pins each 3.2MB feature slice to one XCD's L2 (round-robin
// dispatch). 64 lanes = 32 edges in flight, 2 lanes (float4 each) per edge.
__global__ __launch_bounds__(256) void k_gather(
        const int* __restrict__ rowptr, const int* __restrict__ col,
        const float* __restrict__ hw8, float* __restrict__ agg8) {
    int bid = blockIdx.x;
    int p = bid & 7;
    int ng = bid >> 3;                 // 0..3124
    int t = threadIdx.x;
    int wave = t >> 6, lane = t & 63;
    int g = lane >> 1, f4 = lane & 1;  // edge group / half-slice
    const float* slice = hw8 + (size_t)p * N8;
    float* aslice = agg8 + (size_t)p * N8;
    int ibase = ng * 32 + wave * 8;
#pragma unroll 2
    for (int n = 0; n < 8; ++n) {
        int i = ibase + n;
        int rs = rowptr[i], re = rowptr[i + 1];
        float ax = 0.f, ay = 0.f, az = 0.f, aw = 0.f;
        for (int e = rs; e < re; e += 32) {
            int idx = e + g;
            if (idx < re) {
                int s = col[idx];
                float4 v = *(const float4*)&slice[s * 8 + f4 * 4];
                ax += v.x; ay += v.y; az += v.z; aw += v.w;
            }
        }
#pragma unroll
        for (int st = 2; st <= 32; st <<= 1) {
            ax += __shfl_xor(ax, st); ay += __shfl_xor(ay, st);
            az += __shfl_xor(az, st); aw += __shfl_xor(aw, st);
        }
        if (g == 0) {   // lanes 0 (f4=0) and 1 (f4=1): 32B contiguous store
            float4 r = make_float4(ax, ay, az, aw);
            *(float4*)&aslice[i * 8 + f4 * 4] = r;
        }
    }
}

// ---------------- conv epilogue + relu + next matmul: hw_out' = (relu(di*(agg+self)+b) @ W) * di ----------------
__global__ __launch_bounds__(256) void k_mmg(
        const float* __restrict__ agg8, const float* __restrict__ hw8_in,
        const float* __restrict__ dinv, const float* __restrict__ b,
        const float* __restrict__ W, float* __restrict__ hw8_out) {
    __shared__ float sW[64 * 64];
    __shared__ float sA[4 * 64];
    int t = threadIdx.x;
    const float4* W4 = (const float4*)W;
    float4* sW4 = (float4*)sW;
    for (int i = t; i < 1024; i += 256) sW4[i] = W4[i];
    __syncthreads();

    int wave = t >> 6, lane = t & 63;
    int i = blockIdx.x * 4 + wave;
    float di = dinv[i];
    size_t soff = (size_t)(lane >> 3) * N8 + i * 8 + (lane & 7);
    float a = di * (agg8[soff] + hw8_in[soff]) + b[lane];
    sA[wave * 64 + lane] = fmaxf(a, 0.f);

    // per-wave mm (same-wave LDS ordering; no barrier needed)
    const float4* sA4 = (const float4*)&sA[wave * 64];
    float sum = 0.f;
#pragma unroll
    for (int k4 = 0; k4 < 16; ++k4) {
        float4 a4 = sA4[k4];
        sum = fmaf(a4.x, sW[(k4 * 4 + 0) * 64 + lane], sum);
        sum = fmaf(a4.y, sW[(k4 * 4 + 1) * 64 + lane], sum);
        sum = fmaf(a4.z, sW[(k4 * 4 + 2) * 64 + lane], sum);
        sum = fmaf(a4.w, sW[(k4 * 4 + 3) * 64 + lane], sum);
    }
    hw8_out[soff] = sum * di;
}

// ---------------- segmented mean-pool (no atomics; batch sorted) ----------------
// wave = graph; conv3 epilogue folded: mean_i[di*(agg+self)] + b3 (0 if empty)
__global__ __launch_bounds__(256) void k_pool(
        const float* __restrict__ agg8, const float* __restrict__ hw8,
        const float* __restrict__ dinv, const int* __restrict__ gstart,
        const float* __restrict__ b, float* __restrict__ pooled) {
    int t = threadIdx.x;
    int wave = t >> 6, lane = t & 63;
    int g = blockIdx.x * 4 + wave;
    int n0 = gstart[g], n1 = gstart[g + 1];
    size_t soff = (size_t)(lane >> 3) * N8 + (lane & 7);
    float acc = 0.f;
    int i = n0;
    for (; i + 1 < n1; i += 2) {
        float d0 = dinv[i], d1 = dinv[i + 1];
        float v0 = agg8[soff + (size_t)i * 8] + hw8[soff + (size_t)i * 8];
        float v1 = agg8[soff + (size_t)(i + 1) * 8] + hw8[soff + (size_t)(i + 1) * 8];
        acc = fmaf(d0, v0, acc);
        acc = fmaf(d1, v1, acc);
    }
    if (i < n1) {
        float v = agg8[soff + (size_t)i * 8] + hw8[soff + (size_t)i * 8];
        acc = fmaf(dinv[i], v, acc);
    }
    int n = n1 - n0;
    pooled[g * 64 + lane] = (n > 0) ? (acc / (float)n + b[lane]) : 0.f;
}

// ---------------- dense + softmax + threshold: 8 graphs per block ----------------
__global__ __launch_bounds__(256) void k_dense(
        const float* __restrict__ pooled, const float* __restrict__ Wd,
        const float* __restrict__ bd, float* __restrict__ out) {
    __shared__ float sp[8][64];
    __shared__ float red[8][4];
    int t = threadIdx.x;
    int g0 = blockIdx.x * 8;
    for (int idx = t; idx < 512; idx += 256) {
        int g = idx >> 6, k = idx & 63;
        sp[g][k] = pooled[(g0 + g) * 64 + k];
    }
    __syncthreads();

    float acc[8][8];
#pragma unroll
    for (int r = 0; r < 8; ++r) {
        float bv = bd[r * 256 + t];
#pragma unroll
        for (int g = 0; g < 8; ++g) acc[g][r] = bv;
    }
    for (int k = 0; k < 64; ++k) {
        float w[8];
#pragma unroll
        for (int r = 0; r < 8; ++r) w[r] = Wd[k * BIOPRINT + r * 256 + t];
#pragma unroll
        for (int g = 0; g < 8; ++g) {
            float h = sp[g][k];
#pragma unroll
            for (int r = 0; r < 8; ++r) acc[g][r] = fmaf(h, w[r], acc[g][r]);
        }
    }
    int wave = t >> 6, lane = t & 63;
    float gm[8];
#pragma unroll
    for (int g = 0; g < 8; ++g) {
        float m = acc[g][0];
#pragma unroll
        for (int r = 1; r < 8; ++r) m = fmaxf(m, acc[g][r]);
#pragma unroll
        for (int off = 32; off > 0; off >>= 1) m = fmaxf(m, __shfl_xor(m, off));
        if (lane == 0) red[g][wave] = m;
    }
    __syncthreads();
#pragma unroll
    for (int g = 0; g < 8; ++g)
        gm[g] = fmaxf(fmaxf(red[g][0], red[g][1]), fmaxf(red[g][2], red[g][3]));
    __syncthreads();
    float gs[8];
#pragma unroll
    for (int g = 0; g < 8; ++g) {
        float s = 0.f;
#pragma unroll
        for (int r = 0; r < 8; ++r) { acc[g][r] = expf(acc[g][r] - gm[g]); s += acc[g][r]; }
#pragma unroll
        for (int off = 32; off > 0; off >>= 1) s += __shfl_xor(s, off);
        if (lane == 0) red[g][wave] = s;
    }
    __syncthreads();
#pragma unroll
    for (int g = 0; g < 8; ++g)
        gs[g] = red[g][0] + red[g][1] + red[g][2] + red[g][3];
#pragma unroll
    for (int g = 0; g < 8; ++g)
#pragma unroll
        for (int r = 0; r < 8; ++r) {
            float p = acc[g][r] / gs[g];
            out[(size_t)(g0 + g) * BIOPRINT + r * 256 + t] = (p >= 0.5f) ? 1.0f : 0.0f;
        }
}

// ---------------- launch ----------------

extern "C" void kernel_launch(void* const* d_in, const int* in_sizes, int n_in,
                              void* d_out, int out_size, void* d_ws, size_t ws_size,
                              hipStream_t stream) {
    const float* x     = (const float*)d_in[0];
    const int*   ei    = (const int*)d_in[1];
    const int*   batch = (const int*)d_in[2];
    const float* W1 = (const float*)d_in[3];
    const float* b1 = (const float*)d_in[4];
    const float* W2 = (const float*)d_in[5];
    const float* b2 = (const float*)d_in[6];
    const float* W3 = (const float*)d_in[7];
    const float* b3 = (const float*)d_in[8];
    const float* Wd = (const float*)d_in[9];
    const float* bd = (const float*)d_in[10];
    float* out = (float*)d_out;

    const int* src = ei;
    const int* dst = ei + N_EDGES;

    char* ws = (char*)d_ws;
    size_t off = 0;
    auto alloc = [&](size_t bytes) {
        void* p = ws + off;
        off += (bytes + 255) & ~(size_t)255;
        return p;
    };
    int*   deg    = (int*)alloc(N_NODES * sizeof(int));
    float* dinv   = (float*)alloc(N_NODES * sizeof(float));
    float* pooled = (float*)alloc(N_GRAPHS * HIDDEN * sizeof(float));
    int*   rowptr = (int*)alloc((N_NODES + 1) * sizeof(int));
    int*   bsum   = (int*)alloc(N_SCAN_BLOCKS * sizeof(int));
    int*   cursor = (int*)alloc(N_NODES * sizeof(int));
    int*   gstart = (int*)alloc((N_GRAPHS + 1) * sizeof(int));
    int*   col    = (int*)alloc((size_t)N_EDGES * sizeof(int));
    float* hwA    = (float*)alloc((size_t)N_NODES * HIDDEN * sizeof(float));
    float* hwB    = (float*)alloc((size_t)N_NODES * HIDDEN * sizeof(float));
    float* agg    = (float*)alloc((size_t)N_NODES * HIDDEN * sizeof(float));

    hipMemsetAsync(deg, 0, N_NODES * sizeof(int), stream);

    k_deg<<<(N_EDGES + 255) / 256, 256, 0, stream>>>(dst, deg, N_EDGES);
    k_dinv<<<(N_NODES + 255) / 256, 256, 0, stream>>>(deg, dinv, N_NODES);

    k_scan1<<<N_SCAN_BLOCKS, SCAN_BLK, 0, stream>>>(deg, rowptr, bsum, N_NODES);
    k_scan2<<<1, 64, 0, stream>>>(bsum, N_SCAN_BLOCKS);
    k_scan3<<<N_SCAN_BLOCKS, SCAN_BLK, 0, stream>>>(rowptr, deg, bsum, cursor, N_NODES);
    k_fill<<<(N_EDGES + 255) / 256, 256, 0, stream>>>(src, dst, cursor, col, N_EDGES);
    k_gstart<<<5, 256, 0, stream>>>(batch, gstart);

    const int mm_grid = N_NODES / 4;                 // 25000
    const int ga_grid = (N_NODES / 32) * 8;          // 25000 (3125 groups x 8 slices)
    // layer 1
    k_mm<<<mm_grid, 256, 0, stream>>>(x, W1, dinv, hwA);
    k_gather<<<ga_grid, 256, 0, stream>>>(rowptr, col, hwA, agg);
    k_mmg<<<mm_grid, 256, 0, stream>>>(agg, hwA, dinv, b1, W2, hwB);
    // layer 2
    k_gather<<<ga_grid, 256, 0, stream>>>(rowptr, col, hwB, agg);
    k_mmg<<<mm_grid, 256, 0, stream>>>(agg, hwB, dinv, b2, W3, hwA);
    // layer 3 + pool
    k_gather<<<ga_grid, 256, 0, stream>>>(rowptr, col, hwA, agg);
    k_pool<<<N_GRAPHS / 4, 256, 0, stream>>>(agg, hwA, dinv, gstart, b3, pooled);
    // dense
    k_dense<<<N_GRAPHS / 8, 256, 0, stream>>>(pooled, Wd, bd, out);
}

// Round 6
// 636.216 us; speedup vs baseline: 1.5703x; 1.5703x over previous
//
#include <hip/hip_runtime.h>
#include <math.h>

#define N_NODES   100000
#define N_EDGES   1600000
#define N_FEAT    64
#define HIDDEN    64
#define BIOPRINT  2048
#define N_GRAPHS  1024

#define SCAN_BLK  1024
#define N_SCAN_BLOCKS ((N_NODES + SCAN_BLK - 1) / SCAN_BLK)   // 98

// ---------------- degree / normalization ----------------

__global__ void k_deg(const int* __restrict__ dst, int* __restrict__ deg, int n) {
    int i = blockIdx.x * blockDim.x + threadIdx.x;
    if (i < n) atomicAdd(&deg[dst[i]], 1);
}

__global__ void k_dinv(const int* __restrict__ deg, float* __restrict__ dinv, int n) {
    int i = blockIdx.x * blockDim.x + threadIdx.x;
    if (i < n) dinv[i] = rsqrtf((float)deg[i] + 1.0f);
}

// ---------------- CSR build ----------------

__global__ __launch_bounds__(SCAN_BLK) void k_scan1(
        const int* __restrict__ deg, int* __restrict__ incl,
        int* __restrict__ bsum, int n) {
    __shared__ int tmp[SCAN_BLK];
    int t = threadIdx.x;
    int i = blockIdx.x * SCAN_BLK + t;
    int v = (i < n) ? deg[i] : 0;
    tmp[t] = v;
    __syncthreads();
    for (int off = 1; off < SCAN_BLK; off <<= 1) {
        int u = (t >= off) ? tmp[t - off] : 0;
        __syncthreads();
        tmp[t] += u;
        __syncthreads();
    }
    if (i < n) incl[i] = tmp[t];
    if (t == SCAN_BLK - 1) bsum[blockIdx.x] = tmp[t];
}

__global__ void k_scan2(int* __restrict__ bsum, int nb) {
    if (threadIdx.x == 0 && blockIdx.x == 0) {
        int run = 0;
        for (int b = 0; b < nb; ++b) { int v = bsum[b]; bsum[b] = run; run += v; }
    }
}

__global__ __launch_bounds__(SCAN_BLK) void k_scan3(
        int* __restrict__ rowptr, const int* __restrict__ deg,
        const int* __restrict__ bsum, int* __restrict__ cursor, int n) {
    int i = blockIdx.x * SCAN_BLK + threadIdx.x;
    if (i < n) {
        int ex = rowptr[i] - deg[i] + bsum[blockIdx.x];
        rowptr[i] = ex;
        cursor[i] = ex;
    }
    if (i == 0) rowptr[n] = N_EDGES;
}

__global__ void k_fill(const int* __restrict__ src, const int* __restrict__ dst,
                       int* __restrict__ cursor, int* __restrict__ col, int n) {
    int e = blockIdx.x * blockDim.x + threadIdx.x;
    if (e < n) {
        int s = src[e], d = dst[e];
        int pos = atomicAdd(&cursor[d], 1);
        col[pos] = s;
    }
}

// ---------------- graph segment boundaries (batch is sorted) ----------------
__global__ void k_gstart(const int* __restrict__ batch, int* __restrict__ gstart) {
    int g = blockIdx.x * blockDim.x + threadIdx.x;
    if (g > N_GRAPHS) return;
    if (g == N_GRAPHS) { gstart[g] = N_NODES; return; }
    int lo = 0, hi = N_NODES;
    while (lo < hi) { int mid = (lo + hi) >> 1; if (batch[mid] < g) lo = mid + 1; else hi = mid; }
    gstart[g] = lo;
}

// ---------------- layer-1 matmul: hw1' = (x @ W1) * dinv ----------------
__global__ __launch_bounds__(256) void k_mm(
        const float* __restrict__ h, const float* __restrict__ W,
        const float* __restrict__ dinv, float* __restrict__ hw) {
    __shared__ float sW[64 * 64];
    __shared__ float sH[4 * 64];
    int t = threadIdx.x;
    const float4* W4 = (const float4*)W;
    float4* sW4 = (float4*)sW;
    for (int i = t; i < 1024; i += 256) sW4[i] = W4[i];
    int row0 = blockIdx.x * 4;
    int r = t >> 6, j = t & 63;
    sH[r * 64 + j] = h[(row0 + r) * 64 + j];
    __syncthreads();
    int i = row0 + r;
    float sum = 0.0f;
#pragma unroll
    for (int k = 0; k < 64; ++k) sum = fmaf(sH[r * 64 + k], sW[k * 64 + j], sum);
    hw[i * 64 + j] = sum * dinv[i];
}

// ---------------- fused gather + relu + next matmul (R3 structure, 16-edge unroll) ----------------
// Block = 4 waves = 4 nodes. Quarter q handles edge e+q via float4 row-slice.
// conv_i = dinv[i]*(sum_e hw'[col] + hw'[i]) + b.
__global__ __launch_bounds__(256) void k_gmm(
        const int* __restrict__ rowptr, const int* __restrict__ col,
        const float* __restrict__ dinv, const float* __restrict__ b,
        const float* __restrict__ hw_in, const float* __restrict__ W,
        float* __restrict__ hw_out) {
    __shared__ float sW[64 * 64];
    __shared__ float sA[4 * 64];
    int t = threadIdx.x;
    const float4* W4 = (const float4*)W;
    float4* sW4 = (float4*)sW;
    for (int i = t; i < 1024; i += 256) sW4[i] = W4[i];
    __syncthreads();

    int wave = t >> 6, lane = t & 63;
    int q = lane >> 4, sub = lane & 15;
    int i = blockIdx.x * 4 + wave;
    float di = dinv[i];
    int rs = rowptr[i], re = rowptr[i + 1];
    const float4* hwv = (const float4*)hw_in;
    float4 self4 = hwv[i * 16 + sub];
    float4 b4 = ((const float4*)b)[sub];

    float ax = 0.f, ay = 0.f, az = 0.f, aw = 0.f;     // acc set A
    float bx = 0.f, by = 0.f, bz = 0.f, bw = 0.f;     // acc set B
    int e = rs;
    for (; e + 16 <= re; e += 16) {
        int s0 = col[e + q];
        int s1 = col[e + 4 + q];
        int s2 = col[e + 8 + q];
        int s3 = col[e + 12 + q];
        float4 v0 = hwv[s0 * 16 + sub];
        float4 v1 = hwv[s1 * 16 + sub];
        float4 v2 = hwv[s2 * 16 + sub];
        float4 v3 = hwv[s3 * 16 + sub];
        ax += v0.x; ay += v0.y; az += v0.z; aw += v0.w;
        bx += v1.x; by += v1.y; bz += v1.z; bw += v1.w;
        ax += v2.x; ay += v2.y; az += v2.z; aw += v2.w;
        bx += v3.x; by += v3.y; bz += v3.z; bw += v3.w;
    }
    for (; e + 4 <= re; e += 4) {
        int s0 = col[e + q];
        float4 v0 = hwv[s0 * 16 + sub];
        ax += v0.x; ay += v0.y; az += v0.z; aw += v0.w;
    }
    if (e + q < re) {
        int s0 = col[e + q];
        float4 v0 = hwv[s0 * 16 + sub];
        bx += v0.x; by += v0.y; bz += v0.z; bw += v0.w;
    }
    ax += bx; ay += by; az += bz; aw += bw;
    ax += __shfl_xor(ax, 16); ay += __shfl_xor(ay, 16);
    az += __shfl_xor(az, 16); aw += __shfl_xor(aw, 16);
    ax += __shfl_xor(ax, 32); ay += __shfl_xor(ay, 32);
    az += __shfl_xor(az, 32); aw += __shfl_xor(aw, 32);

    float4 r;
    r.x = fmaxf(fmaf(di, ax + self4.x, b4.x), 0.f);
    r.y = fmaxf(fmaf(di, ay + self4.y, b4.y), 0.f);
    r.z = fmaxf(fmaf(di, az + self4.z, b4.z), 0.f);
    r.w = fmaxf(fmaf(di, aw + self4.w, b4.w), 0.f);
    if (q == 0) ((float4*)&sA[wave * 64])[sub] = r;

    // per-wave mm (same-wave LDS ordering; barrier above covers sW)
    const float4* sA4 = (const float4*)&sA[wave * 64];
    float sum = 0.f;
#pragma unroll
    for (int k4 = 0; k4 < 16; ++k4) {
        float4 a4 = sA4[k4];
        sum = fmaf(a4.x, sW[(k4 * 4 + 0) * 64 + lane], sum);
        sum = fmaf(a4.y, sW[(k4 * 4 + 1) * 64 + lane], sum);
        sum = fmaf(a4.z, sW[(k4 * 4 + 2) * 64 + lane], sum);
        sum = fmaf(a4.w, sW[(k4 * 4 + 3) * 64 + lane], sum);
    }
    hw_out[i * 64 + lane] = sum * di;   // pre-scale for next layer's gather
}

// ---------------- layer-3 gather: conv3 (no relu), flat write, no atomics ----------------
__global__ __launch_bounds__(256) void k_gather3(
        const int* __restrict__ rowptr, const int* __restrict__ col,
        const float* __restrict__ dinv, const float* __restrict__ b,
        const float* __restrict__ hw_in, float* __restrict__ conv) {
    int t = threadIdx.x;
    int wave = t >> 6, lane = t & 63;
    int q = lane >> 4, sub = lane & 15;
    int i = blockIdx.x * 4 + wave;
    float di = dinv[i];
    int rs = rowptr[i], re = rowptr[i + 1];
    const float4* hwv = (const float4*)hw_in;
    float4 self4 = hwv[i * 16 + sub];
    float4 b4 = ((const float4*)b)[sub];

    float ax = 0.f, ay = 0.f, az = 0.f, aw = 0.f;
    float bx = 0.f, by = 0.f, bz = 0.f, bw = 0.f;
    int e = rs;
    for (; e + 16 <= re; e += 16) {
        int s0 = col[e + q];
        int s1 = col[e + 4 + q];
        int s2 = col[e + 8 + q];
        int s3 = col[e + 12 + q];
        float4 v0 = hwv[s0 * 16 + sub];
        float4 v1 = hwv[s1 * 16 + sub];
        float4 v2 = hwv[s2 * 16 + sub];
        float4 v3 = hwv[s3 * 16 + sub];
        ax += v0.x; ay += v0.y; az += v0.z; aw += v0.w;
        bx += v1.x; by += v1.y; bz += v1.z; bw += v1.w;
        ax += v2.x; ay += v2.y; az += v2.z; aw += v2.w;
        bx += v3.x; by += v3.y; bz += v3.z; bw += v3.w;
    }
    for (; e + 4 <= re; e += 4) {
        int s0 = col[e + q];
        float4 v0 = hwv[s0 * 16 + sub];
        ax += v0.x; ay += v0.y; az += v0.z; aw += v0.w;
    }
    if (e + q < re) {
        int s0 = col[e + q];
        float4 v0 = hwv[s0 * 16 + sub];
        bx += v0.x; by += v0.y; bz += v0.z; bw += v0.w;
    }
    ax += bx; ay += by; az += bz; aw += bw;
    ax += __shfl_xor(ax, 16); ay += __shfl_xor(ay, 16);
    az += __shfl_xor(az, 16); aw += __shfl_xor(aw, 16);
    ax += __shfl_xor(ax, 32); ay += __shfl_xor(ay, 32);
    az += __shfl_xor(az, 32); aw += __shfl_xor(aw, 32);

    if (q == 0) {
        float4 r;
        r.x = fmaf(di, ax + self4.x, b4.x);
        r.y = fmaf(di, ay + self4.y, b4.y);
        r.z = fmaf(di, az + self4.z, b4.z);
        r.w = fmaf(di, aw + self4.w, b4.w);
        ((float4*)&conv[i * 64])[sub] = r;
    }
}

// ---------------- segmented mean-pool (batch sorted; no atomics) ----------------
// wave = graph, lane = feature; rows sequential (coalesced 256B reads)
__global__ __launch_bounds__(256) void k_pool(
        const float* __restrict__ conv, const int* __restrict__ gstart,
        float* __restrict__ pooled) {
    int t = threadIdx.x;
    int wave = t >> 6, lane = t & 63;
    int g = blockIdx.x * 4 + wave;
    int n0 = gstart[g], n1 = gstart[g + 1];
    float acc = 0.f;
    for (int i = n0; i < n1; ++i) acc += conv[(size_t)i * 64 + lane];
    int n = n1 - n0;
    pooled[g * 64 + lane] = (n > 0) ? acc / (float)n : 0.f;
}

// ---------------- dense + softmax + threshold: 8 graphs per block ----------------
__global__ __launch_bounds__(256) void k_dense(
        const float* __restrict__ pooled, const float* __restrict__ Wd,
        const float* __restrict__ bd, float* __restrict__ out) {
    __shared__ float sp[8][64];
    __shared__ float red[8][4];
    int t = threadIdx.x;
    int g0 = blockIdx.x * 8;
    for (int idx = t; idx < 512; idx += 256) {
        int g = idx >> 6, k = idx & 63;
        sp[g][k] = pooled[(g0 + g) * 64 + k];
    }
    __syncthreads();

    float acc[8][8];
#pragma unroll
    for (int r = 0; r < 8; ++r) {
        float bv = bd[r * 256 + t];
#pragma unroll
        for (int g = 0; g < 8; ++g) acc[g][r] = bv;
    }
    for (int k = 0; k < 64; ++k) {
        float w[8];
#pragma unroll
        for (int r = 0; r < 8; ++r) w[r] = Wd[k * BIOPRINT + r * 256 + t];
#pragma unroll
        for (int g = 0; g < 8; ++g) {
            float h = sp[g][k];
#pragma unroll
            for (int r = 0; r < 8; ++r) acc[g][r] = fmaf(h, w[r], acc[g][r]);
        }
    }
    int wave = t >> 6, lane = t & 63;
    float gm[8];
#pragma unroll
    for (int g = 0; g < 8; ++g) {
        float m = acc[g][0];
#pragma unroll
        for (int r = 1; r < 8; ++r) m = fmaxf(m, acc[g][r]);
#pragma unroll
        for (int off = 32; off > 0; off >>= 1) m = fmaxf(m, __shfl_xor(m, off));
        if (lane == 0) red[g][wave] = m;
    }
    __syncthreads();
#pragma unroll
    for (int g = 0; g < 8; ++g)
        gm[g] = fmaxf(fmaxf(red[g][0], red[g][1]), fmaxf(red[g][2], red[g][3]));
    __syncthreads();
    float gs[8];
#pragma unroll
    for (int g = 0; g < 8; ++g) {
        float s = 0.f;
#pragma unroll
        for (int r = 0; r < 8; ++r) { acc[g][r] = expf(acc[g][r] - gm[g]); s += acc[g][r]; }
#pragma unroll
        for (int off = 32; off > 0; off >>= 1) s += __shfl_xor(s, off);
        if (lane == 0) red[g][wave] = s;
    }
    __syncthreads();
#pragma unroll
    for (int g = 0; g < 8; ++g)
        gs[g] = red[g][0] + red[g][1] + red[g][2] + red[g][3];
#pragma unroll
    for (int g = 0; g < 8; ++g)
#pragma unroll
        for (int r = 0; r < 8; ++r) {
            float p = acc[g][r] / gs[g];
            out[(size_t)(g0 + g) * BIOPRINT + r * 256 + t] = (p >= 0.5f) ? 1.0f : 0.0f;
        }
}

// ---------------- launch ----------------

extern "C" void kernel_launch(void* const* d_in, const int* in_sizes, int n_in,
                              void* d_out, int out_size, void* d_ws, size_t ws_size,
                              hipStream_t stream) {
    const float* x     = (const float*)d_in[0];
    const int*   ei    = (const int*)d_in[1];
    const int*   batch = (const int*)d_in[2];
    const float* W1 = (const float*)d_in[3];
    const float* b1 = (const float*)d_in[4];
    const float* W2 = (const float*)d_in[5];
    const float* b2 = (const float*)d_in[6];
    const float* W3 = (const float*)d_in[7];
    const float* b3 = (const float*)d_in[8];
    const float* Wd = (const float*)d_in[9];
    const float* bd = (const float*)d_in[10];
    float* out = (float*)d_out;

    const int* src = ei;
    const int* dst = ei + N_EDGES;

    char* ws = (char*)d_ws;
    size_t off = 0;
    auto alloc = [&](size_t bytes) {
        void* p = ws + off;
        off += (bytes + 255) & ~(size_t)255;
        return p;
    };
    int*   deg    = (int*)alloc(N_NODES * sizeof(int));
    float* dinv   = (float*)alloc(N_NODES * sizeof(float));
    float* pooled = (float*)alloc(N_GRAPHS * HIDDEN * sizeof(float));
    int*   rowptr = (int*)alloc((N_NODES + 1) * sizeof(int));
    int*   bsum   = (int*)alloc(N_SCAN_BLOCKS * sizeof(int));
    int*   cursor = (int*)alloc(N_NODES * sizeof(int));
    int*   gstart = (int*)alloc((N_GRAPHS + 1) * sizeof(int));
    int*   col    = (int*)alloc((size_t)N_EDGES * sizeof(int));
    float* bufA   = (float*)alloc((size_t)N_NODES * HIDDEN * sizeof(float));
    float* bufB   = (float*)alloc((size_t)N_NODES * HIDDEN * sizeof(float));

    hipMemsetAsync(deg, 0, N_NODES * sizeof(int), stream);

    k_deg<<<(N_EDGES + 255) / 256, 256, 0, stream>>>(dst, deg, N_EDGES);
    k_dinv<<<(N_NODES + 255) / 256, 256, 0, stream>>>(deg, dinv, N_NODES);

    k_scan1<<<N_SCAN_BLOCKS, SCAN_BLK, 0, stream>>>(deg, rowptr, bsum, N_NODES);
    k_scan2<<<1, 64, 0, stream>>>(bsum, N_SCAN_BLOCKS);
    k_scan3<<<N_SCAN_BLOCKS, SCAN_BLK, 0, stream>>>(rowptr, deg, bsum, cursor, N_NODES);
    k_fill<<<(N_EDGES + 255) / 256, 256, 0, stream>>>(src, dst, cursor, col, N_EDGES);
    k_gstart<<<5, 256, 0, stream>>>(batch, gstart);

    const int mm_grid = N_NODES / 4;          // 25000
    // layer 1: hw1' = (x @ W1) * dinv -> A
    k_mm<<<mm_grid, 256, 0, stream>>>(x, W1, dinv, bufA);
    // conv1 + relu + @W2 (scaled) -> B
    k_gmm<<<mm_grid, 256, 0, stream>>>(rowptr, col, dinv, b1, bufA, W2, bufB);
    // conv2 + relu + @W3 (scaled) -> A
    k_gmm<<<mm_grid, 256, 0, stream>>>(rowptr, col, dinv, b2, bufB, W3, bufA);
    // conv3 (no relu) -> B
    k_gather3<<<mm_grid, 256, 0, stream>>>(rowptr, col, dinv, b3, bufA, bufB);
    // segmented mean-pool
    k_pool<<<N_GRAPHS / 4, 256, 0, stream>>>(bufB, gstart, pooled);
    // dense + softmax + threshold (8 graphs/block)
    k_dense<<<N_GRAPHS / 8, 256, 0, stream>>>(pooled, Wd, bd, out);
}

// Round 7
// 618.949 us; speedup vs baseline: 1.6141x; 1.0279x over previous
//
#include <hip/hip_runtime.h>
#include <math.h>

#define N_NODES   100000
#define N_EDGES   1600000
#define N_FEAT    64
#define HIDDEN    64
#define BIOPRINT  2048
#define N_GRAPHS  1024

#define SCAN_BLK  1024
#define N_SCAN_BLOCKS ((N_NODES + SCAN_BLK - 1) / SCAN_BLK)   // 98
#define FILL_SLICE 25000                                       // 4 passes

// ---------------- degree / normalization ----------------

__global__ void k_deg(const int* __restrict__ dst, int* __restrict__ deg, int n) {
    int i = blockIdx.x * blockDim.x + threadIdx.x;
    if (i < n) atomicAdd(&deg[__builtin_nontemporal_load(&dst[i])], 1);
}

__global__ void k_dinv(const int* __restrict__ deg, float* __restrict__ dinv, int n) {
    int i = blockIdx.x * blockDim.x + threadIdx.x;
    if (i < n) dinv[i] = rsqrtf((float)deg[i] + 1.0f);
}

// ---------------- CSR build ----------------

__global__ __launch_bounds__(SCAN_BLK) void k_scan1(
        const int* __restrict__ deg, int* __restrict__ incl,
        int* __restrict__ bsum, int n) {
    __shared__ int tmp[SCAN_BLK];
    int t = threadIdx.x;
    int i = blockIdx.x * SCAN_BLK + t;
    int v = (i < n) ? deg[i] : 0;
    tmp[t] = v;
    __syncthreads();
    for (int off = 1; off < SCAN_BLK; off <<= 1) {
        int u = (t >= off) ? tmp[t - off] : 0;
        __syncthreads();
        tmp[t] += u;
        __syncthreads();
    }
    if (i < n) incl[i] = tmp[t];
    if (t == SCAN_BLK - 1) bsum[blockIdx.x] = tmp[t];
}

__global__ void k_scan2(int* __restrict__ bsum, int nb) {
    if (threadIdx.x == 0 && blockIdx.x == 0) {
        int run = 0;
        for (int b = 0; b < nb; ++b) { int v = bsum[b]; bsum[b] = run; run += v; }
    }
}

__global__ __launch_bounds__(SCAN_BLK) void k_scan3(
        int* __restrict__ rowptr, const int* __restrict__ deg,
        const int* __restrict__ bsum, int* __restrict__ cursor, int n) {
    int i = blockIdx.x * SCAN_BLK + threadIdx.x;
    if (i < n) {
        int ex = rowptr[i] - deg[i] + bsum[blockIdx.x];
        rowptr[i] = ex;
        cursor[i] = ex;
    }
    if (i == 0) rowptr[n] = N_EDGES;
}

// fill pass: only edges whose dst falls in [lo,hi) — write slice stays L2-resident.
// nt loads keep the streaming edge list out of L2.
__global__ void k_fillp(const int* __restrict__ src, const int* __restrict__ dst,
                        int* __restrict__ cursor, int* __restrict__ col,
                        int lo, int hi, int n) {
    int e = blockIdx.x * blockDim.x + threadIdx.x;
    if (e < n) {
        int d = __builtin_nontemporal_load(&dst[e]);
        if (d >= lo && d < hi) {
            int s = __builtin_nontemporal_load(&src[e]);
            int pos = atomicAdd(&cursor[d], 1);
            col[pos] = s;
        }
    }
}

// ---------------- graph segment boundaries (batch is sorted) ----------------
__global__ void k_gstart(const int* __restrict__ batch, int* __restrict__ gstart) {
    int g = blockIdx.x * blockDim.x + threadIdx.x;
    if (g > N_GRAPHS) return;
    if (g == N_GRAPHS) { gstart[g] = N_NODES; return; }
    int lo = 0, hi = N_NODES;
    while (lo < hi) { int mid = (lo + hi) >> 1; if (batch[mid] < g) lo = mid + 1; else hi = mid; }
    gstart[g] = lo;
}

// ---------------- layer-1 matmul: hw1' = (x @ W1) * dinv ----------------
__global__ __launch_bounds__(256) void k_mm(
        const float* __restrict__ h, const float* __restrict__ W,
        const float* __restrict__ dinv, float* __restrict__ hw) {
    __shared__ float sW[64 * 64];
    __shared__ float sH[4 * 64];
    int t = threadIdx.x;
    const float4* W4 = (const float4*)W;
    float4* sW4 = (float4*)sW;
    for (int i = t; i < 1024; i += 256) sW4[i] = W4[i];
    int row0 = blockIdx.x * 4;
    int r = t >> 6, j = t & 63;
    sH[r * 64 + j] = h[(row0 + r) * 64 + j];
    __syncthreads();
    int i = row0 + r;
    float sum = 0.0f;
#pragma unroll
    for (int k = 0; k < 64; ++k) sum = fmaf(sH[r * 64 + k], sW[k * 64 + j], sum);
    hw[i * 64 + j] = sum * dinv[i];
}

// ---------------- fused gather + relu + next matmul ----------------
__global__ __launch_bounds__(256) void k_gmm(
        const int* __restrict__ rowptr, const int* __restrict__ col,
        const float* __restrict__ dinv, const float* __restrict__ b,
        const float* __restrict__ hw_in, const float* __restrict__ W,
        float* __restrict__ hw_out) {
    __shared__ float sW[64 * 64];
    __shared__ float sA[4 * 64];
    int t = threadIdx.x;
    const float4* W4 = (const float4*)W;
    float4* sW4 = (float4*)sW;
    for (int i = t; i < 1024; i += 256) sW4[i] = W4[i];
    __syncthreads();

    int wave = t >> 6, lane = t & 63;
    int q = lane >> 4, sub = lane & 15;
    int i = blockIdx.x * 4 + wave;
    float di = dinv[i];
    int rs = rowptr[i], re = rowptr[i + 1];
    const float4* hwv = (const float4*)hw_in;
    float4 self4 = hwv[i * 16 + sub];
    float4 b4 = ((const float4*)b)[sub];

    float ax = 0.f, ay = 0.f, az = 0.f, aw = 0.f;
    float bx = 0.f, by = 0.f, bz = 0.f, bw = 0.f;
    int e = rs;
    for (; e + 16 <= re; e += 16) {
        int s0 = __builtin_nontemporal_load(&col[e + q]);
        int s1 = __builtin_nontemporal_load(&col[e + 4 + q]);
        int s2 = __builtin_nontemporal_load(&col[e + 8 + q]);
        int s3 = __builtin_nontemporal_load(&col[e + 12 + q]);
        float4 v0 = hwv[s0 * 16 + sub];
        float4 v1 = hwv[s1 * 16 + sub];
        float4 v2 = hwv[s2 * 16 + sub];
        float4 v3 = hwv[s3 * 16 + sub];
        ax += v0.x; ay += v0.y; az += v0.z; aw += v0.w;
        bx += v1.x; by += v1.y; bz += v1.z; bw += v1.w;
        ax += v2.x; ay += v2.y; az += v2.z; aw += v2.w;
        bx += v3.x; by += v3.y; bz += v3.z; bw += v3.w;
    }
    for (; e + 4 <= re; e += 4) {
        int s0 = col[e + q];
        float4 v0 = hwv[s0 * 16 + sub];
        ax += v0.x; ay += v0.y; az += v0.z; aw += v0.w;
    }
    if (e + q < re) {
        int s0 = col[e + q];
        float4 v0 = hwv[s0 * 16 + sub];
        bx += v0.x; by += v0.y; bz += v0.z; bw += v0.w;
    }
    ax += bx; ay += by; az += bz; aw += bw;
    ax += __shfl_xor(ax, 16); ay += __shfl_xor(ay, 16);
    az += __shfl_xor(az, 16); aw += __shfl_xor(aw, 16);
    ax += __shfl_xor(ax, 32); ay += __shfl_xor(ay, 32);
    az += __shfl_xor(az, 32); aw += __shfl_xor(aw, 32);

    float4 r;
    r.x = fmaxf(fmaf(di, ax + self4.x, b4.x), 0.f);
    r.y = fmaxf(fmaf(di, ay + self4.y, b4.y), 0.f);
    r.z = fmaxf(fmaf(di, az + self4.z, b4.z), 0.f);
    r.w = fmaxf(fmaf(di, aw + self4.w, b4.w), 0.f);
    if (q == 0) ((float4*)&sA[wave * 64])[sub] = r;

    const float4* sA4 = (const float4*)&sA[wave * 64];
    float sum = 0.f;
#pragma unroll
    for (int k4 = 0; k4 < 16; ++k4) {
        float4 a4 = sA4[k4];
        sum = fmaf(a4.x, sW[(k4 * 4 + 0) * 64 + lane], sum);
        sum = fmaf(a4.y, sW[(k4 * 4 + 1) * 64 + lane], sum);
        sum = fmaf(a4.z, sW[(k4 * 4 + 2) * 64 + lane], sum);
        sum = fmaf(a4.w, sW[(k4 * 4 + 3) * 64 + lane], sum);
    }
    hw_out[i * 64 + lane] = sum * di;
}

// ---------------- layer-3 gather: conv3 (no relu), flat write ----------------
__global__ __launch_bounds__(256) void k_gather3(
        const int* __restrict__ rowptr, const int* __restrict__ col,
        const float* __restrict__ dinv, const float* __restrict__ b,
        const float* __restrict__ hw_in, float* __restrict__ conv) {
    int t = threadIdx.x;
    int wave = t >> 6, lane = t & 63;
    int q = lane >> 4, sub = lane & 15;
    int i = blockIdx.x * 4 + wave;
    float di = dinv[i];
    int rs = rowptr[i], re = rowptr[i + 1];
    const float4* hwv = (const float4*)hw_in;
    float4 self4 = hwv[i * 16 + sub];
    float4 b4 = ((const float4*)b)[sub];

    float ax = 0.f, ay = 0.f, az = 0.f, aw = 0.f;
    float bx = 0.f, by = 0.f, bz = 0.f, bw = 0.f;
    int e = rs;
    for (; e + 16 <= re; e += 16) {
        int s0 = __builtin_nontemporal_load(&col[e + q]);
        int s1 = __builtin_nontemporal_load(&col[e + 4 + q]);
        int s2 = __builtin_nontemporal_load(&col[e + 8 + q]);
        int s3 = __builtin_nontemporal_load(&col[e + 12 + q]);
        float4 v0 = hwv[s0 * 16 + sub];
        float4 v1 = hwv[s1 * 16 + sub];
        float4 v2 = hwv[s2 * 16 + sub];
        float4 v3 = hwv[s3 * 16 + sub];
        ax += v0.x; ay += v0.y; az += v0.z; aw += v0.w;
        bx += v1.x; by += v1.y; bz += v1.z; bw += v1.w;
        ax += v2.x; ay += v2.y; az += v2.z; aw += v2.w;
        bx += v3.x; by += v3.y; bz += v3.z; bw += v3.w;
    }
    for (; e + 4 <= re; e += 4) {
        int s0 = col[e + q];
        float4 v0 = hwv[s0 * 16 + sub];
        ax += v0.x; ay += v0.y; az += v0.z; aw += v0.w;
    }
    if (e + q < re) {
        int s0 = col[e + q];
        float4 v0 = hwv[s0 * 16 + sub];
        bx += v0.x; by += v0.y; bz += v0.z; bw += v0.w;
    }
    ax += bx; ay += by; az += bz; aw += bw;
    ax += __shfl_xor(ax, 16); ay += __shfl_xor(ay, 16);
    az += __shfl_xor(az, 16); aw += __shfl_xor(aw, 16);
    ax += __shfl_xor(ax, 32); ay += __shfl_xor(ay, 32);
    az += __shfl_xor(az, 32); aw += __shfl_xor(aw, 32);

    if (q == 0) {
        float4 r;
        r.x = fmaf(di, ax + self4.x, b4.x);
        r.y = fmaf(di, ay + self4.y, b4.y);
        r.z = fmaf(di, az + self4.z, b4.z);
        r.w = fmaf(di, aw + self4.w, b4.w);
        ((float4*)&conv[i * 64])[sub] = r;
    }
}

// ---------------- segmented mean-pool ----------------
__global__ __launch_bounds__(256) void k_pool(
        const float* __restrict__ conv, const int* __restrict__ gstart,
        float* __restrict__ pooled) {
    int t = threadIdx.x;
    int wave = t >> 6, lane = t & 63;
    int g = blockIdx.x * 4 + wave;
    int n0 = gstart[g], n1 = gstart[g + 1];
    float acc = 0.f;
    for (int i = n0; i < n1; ++i) acc += conv[(size_t)i * 64 + lane];
    int n = n1 - n0;
    pooled[g * 64 + lane] = (n > 0) ? acc / (float)n : 0.f;
}

// ---------------- dense + softmax + threshold: 8 graphs per block ----------------
__global__ __launch_bounds__(256) void k_dense(
        const float* __restrict__ pooled, const float* __restrict__ Wd,
        const float* __restrict__ bd, float* __restrict__ out) {
    __shared__ float sp[8][64];
    __shared__ float red[8][4];
    int t = threadIdx.x;
    int g0 = blockIdx.x * 8;
    for (int idx = t; idx < 512; idx += 256) {
        int g = idx >> 6, k = idx & 63;
        sp[g][k] = pooled[(g0 + g) * 64 + k];
    }
    __syncthreads();

    float acc[8][8];
#pragma unroll
    for (int r = 0; r < 8; ++r) {
        float bv = bd[r * 256 + t];
#pragma unroll
        for (int g = 0; g < 8; ++g) acc[g][r] = bv;
    }
    for (int k = 0; k < 64; ++k) {
        float w[8];
#pragma unroll
        for (int r = 0; r < 8; ++r) w[r] = Wd[k * BIOPRINT + r * 256 + t];
#pragma unroll
        for (int g = 0; g < 8; ++g) {
            float h = sp[g][k];
#pragma unroll
            for (int r = 0; r < 8; ++r) acc[g][r] = fmaf(h, w[r], acc[g][r]);
        }
    }
    int wave = t >> 6, lane = t & 63;
    float gm[8];
#pragma unroll
    for (int g = 0; g < 8; ++g) {
        float m = acc[g][0];
#pragma unroll
        for (int r = 1; r < 8; ++r) m = fmaxf(m, acc[g][r]);
#pragma unroll
        for (int off = 32; off > 0; off >>= 1) m = fmaxf(m, __shfl_xor(m, off));
        if (lane == 0) red[g][wave] = m;
    }
    __syncthreads();
#pragma unroll
    for (int g = 0; g < 8; ++g)
        gm[g] = fmaxf(fmaxf(red[g][0], red[g][1]), fmaxf(red[g][2], red[g][3]));
    __syncthreads();
    float gs[8];
#pragma unroll
    for (int g = 0; g < 8; ++g) {
        float s = 0.f;
#pragma unroll
        for (int r = 0; r < 8; ++r) { acc[g][r] = expf(acc[g][r] - gm[g]); s += acc[g][r]; }
#pragma unroll
        for (int off = 32; off > 0; off >>= 1) s += __shfl_xor(s, off);
        if (lane == 0) red[g][wave] = s;
    }
    __syncthreads();
#pragma unroll
    for (int g = 0; g < 8; ++g)
        gs[g] = red[g][0] + red[g][1] + red[g][2] + red[g][3];
#pragma unroll
    for (int g = 0; g < 8; ++g)
#pragma unroll
        for (int r = 0; r < 8; ++r) {
            float p = acc[g][r] / gs[g];
            out[(size_t)(g0 + g) * BIOPRINT + r * 256 + t] = (p >= 0.5f) ? 1.0f : 0.0f;
        }
}

// ---------------- launch ----------------

extern "C" void kernel_launch(void* const* d_in, const int* in_sizes, int n_in,
                              void* d_out, int out_size, void* d_ws, size_t ws_size,
                              hipStream_t stream) {
    const float* x     = (const float*)d_in[0];
    const int*   ei    = (const int*)d_in[1];
    const int*   batch = (const int*)d_in[2];
    const float* W1 = (const float*)d_in[3];
    const float* b1 = (const float*)d_in[4];
    const float* W2 = (const float*)d_in[5];
    const float* b2 = (const float*)d_in[6];
    const float* W3 = (const float*)d_in[7];
    const float* b3 = (const float*)d_in[8];
    const float* Wd = (const float*)d_in[9];
    const float* bd = (const float*)d_in[10];
    float* out = (float*)d_out;

    const int* src = ei;
    const int* dst = ei + N_EDGES;

    char* ws = (char*)d_ws;
    size_t off = 0;
    auto alloc = [&](size_t bytes) {
        void* p = ws + off;
        off += (bytes + 255) & ~(size_t)255;
        return p;
    };
    int*   deg    = (int*)alloc(N_NODES * sizeof(int));
    float* dinv   = (float*)alloc(N_NODES * sizeof(float));
    float* pooled = (float*)alloc(N_GRAPHS * HIDDEN * sizeof(float));
    int*   rowptr = (int*)alloc((N_NODES + 1) * sizeof(int));
    int*   bsum   = (int*)alloc(N_SCAN_BLOCKS * sizeof(int));
    int*   cursor = (int*)alloc(N_NODES * sizeof(int));
    int*   gstart = (int*)alloc((N_GRAPHS + 1) * sizeof(int));
    int*   col    = (int*)alloc((size_t)N_EDGES * sizeof(int));
    float* bufA   = (float*)alloc((size_t)N_NODES * HIDDEN * sizeof(float));
    float* bufB   = (float*)alloc((size_t)N_NODES * HIDDEN * sizeof(float));

    hipMemsetAsync(deg, 0, N_NODES * sizeof(int), stream);

    k_deg<<<(N_EDGES + 255) / 256, 256, 0, stream>>>(dst, deg, N_EDGES);
    k_dinv<<<(N_NODES + 255) / 256, 256, 0, stream>>>(deg, dinv, N_NODES);

    k_scan1<<<N_SCAN_BLOCKS, SCAN_BLK, 0, stream>>>(deg, rowptr, bsum, N_NODES);
    k_scan2<<<1, 64, 0, stream>>>(bsum, N_SCAN_BLOCKS);
    k_scan3<<<N_SCAN_BLOCKS, SCAN_BLK, 0, stream>>>(rowptr, deg, bsum, cursor, N_NODES);
    // cache-blocked counting-sort fill: 4 serialized range-filtered passes
    for (int p = 0; p < 4; ++p) {
        k_fillp<<<(N_EDGES + 255) / 256, 256, 0, stream>>>(
            src, dst, cursor, col, p * FILL_SLICE, (p + 1) * FILL_SLICE, N_EDGES);
    }
    k_gstart<<<5, 256, 0, stream>>>(batch, gstart);

    const int mm_grid = N_NODES / 4;          // 25000
    k_mm<<<mm_grid, 256, 0, stream>>>(x, W1, dinv, bufA);
    k_gmm<<<mm_grid, 256, 0, stream>>>(rowptr, col, dinv, b1, bufA, W2, bufB);
    k_gmm<<<mm_grid, 256, 0, stream>>>(rowptr, col, dinv, b2, bufB, W3, bufA);
    k_gather3<<<mm_grid, 256, 0, stream>>>(rowptr, col, dinv, b3, bufA, bufB);
    k_pool<<<N_GRAPHS / 4, 256, 0, stream>>>(bufB, gstart, pooled);
    k_dense<<<N_GRAPHS / 8, 256, 0, stream>>>(pooled, Wd, bd, out);
}

// Round 8
// 592.130 us; speedup vs baseline: 1.6872x; 1.0453x over previous
//
#include <hip/hip_runtime.h>
#include <hip/hip_fp16.h>
#include <math.h>

#define N_NODES   100000
#define N_EDGES   1600000
#define N_FEAT    64
#define HIDDEN    64
#define BIOPRINT  2048
#define N_GRAPHS  1024

#define SCAN_BLK  1024
#define N_SCAN_BLOCKS ((N_NODES + SCAN_BLK - 1) / SCAN_BLK)   // 98
#define FILL_SLICE 25000                                       // 4 passes

__device__ __forceinline__ float4 h4_to_f4(uint2 u) {
    __half2 p0 = *(__half2*)&u.x;
    __half2 p1 = *(__half2*)&u.y;
    float2 f0 = __half22float2(p0);
    float2 f1 = __half22float2(p1);
    return make_float4(f0.x, f0.y, f1.x, f1.y);
}

// ---------------- degree / normalization ----------------

__global__ void k_deg(const int* __restrict__ dst, int* __restrict__ deg, int n) {
    int i = blockIdx.x * blockDim.x + threadIdx.x;
    if (i < n) atomicAdd(&deg[__builtin_nontemporal_load(&dst[i])], 1);
}

__global__ void k_dinv(const int* __restrict__ deg, float* __restrict__ dinv, int n) {
    int i = blockIdx.x * blockDim.x + threadIdx.x;
    if (i < n) dinv[i] = rsqrtf((float)deg[i] + 1.0f);
}

// ---------------- CSR build ----------------

__global__ __launch_bounds__(SCAN_BLK) void k_scan1(
        const int* __restrict__ deg, int* __restrict__ incl,
        int* __restrict__ bsum, int n) {
    __shared__ int tmp[SCAN_BLK];
    int t = threadIdx.x;
    int i = blockIdx.x * SCAN_BLK + t;
    int v = (i < n) ? deg[i] : 0;
    tmp[t] = v;
    __syncthreads();
    for (int off = 1; off < SCAN_BLK; off <<= 1) {
        int u = (t >= off) ? tmp[t - off] : 0;
        __syncthreads();
        tmp[t] += u;
        __syncthreads();
    }
    if (i < n) incl[i] = tmp[t];
    if (t == SCAN_BLK - 1) bsum[blockIdx.x] = tmp[t];
}

__global__ void k_scan2(int* __restrict__ bsum, int nb) {
    if (threadIdx.x == 0 && blockIdx.x == 0) {
        int run = 0;
        for (int b = 0; b < nb; ++b) { int v = bsum[b]; bsum[b] = run; run += v; }
    }
}

__global__ __launch_bounds__(SCAN_BLK) void k_scan3(
        int* __restrict__ rowptr, const int* __restrict__ deg,
        const int* __restrict__ bsum, int* __restrict__ cursor, int n) {
    int i = blockIdx.x * SCAN_BLK + threadIdx.x;
    if (i < n) {
        int ex = rowptr[i] - deg[i] + bsum[blockIdx.x];
        rowptr[i] = ex;
        cursor[i] = ex;
    }
    if (i == 0) rowptr[n] = N_EDGES;
}

// fill pass: range-filtered so the write slice stays L2-resident
__global__ void k_fillp(const int* __restrict__ src, const int* __restrict__ dst,
                        int* __restrict__ cursor, int* __restrict__ col,
                        int lo, int hi, int n) {
    int e = blockIdx.x * blockDim.x + threadIdx.x;
    if (e < n) {
        int d = __builtin_nontemporal_load(&dst[e]);
        if (d >= lo && d < hi) {
            int s = __builtin_nontemporal_load(&src[e]);
            int pos = atomicAdd(&cursor[d], 1);
            col[pos] = s;
        }
    }
}

// ---------------- graph segment boundaries (batch is sorted) ----------------
__global__ void k_gstart(const int* __restrict__ batch, int* __restrict__ gstart) {
    int g = blockIdx.x * blockDim.x + threadIdx.x;
    if (g > N_GRAPHS) return;
    if (g == N_GRAPHS) { gstart[g] = N_NODES; return; }
    int lo = 0, hi = N_NODES;
    while (lo < hi) { int mid = (lo + hi) >> 1; if (batch[mid] < g) lo = mid + 1; else hi = mid; }
    gstart[g] = lo;
}

// ---------------- layer-1 matmul: hw1' = fp16[(x @ W1) * dinv] ----------------
__global__ __launch_bounds__(256) void k_mm(
        const float* __restrict__ h, const float* __restrict__ W,
        const float* __restrict__ dinv, __half* __restrict__ hw) {
    __shared__ float sW[64 * 64];
    __shared__ float sH[4 * 64];
    int t = threadIdx.x;
    const float4* W4 = (const float4*)W;
    float4* sW4 = (float4*)sW;
    for (int i = t; i < 1024; i += 256) sW4[i] = W4[i];
    int row0 = blockIdx.x * 4;
    int r = t >> 6, j = t & 63;
    sH[r * 64 + j] = h[(row0 + r) * 64 + j];
    __syncthreads();
    int i = row0 + r;
    float sum = 0.0f;
#pragma unroll
    for (int k = 0; k < 64; ++k) sum = fmaf(sH[r * 64 + k], sW[k * 64 + j], sum);
    hw[i * 64 + j] = __float2half_rn(sum * dinv[i]);
}

// ---------------- fused gather(fp16) + relu + next matmul ----------------
// Row = 128B = one L2 line. Quarter q handles edge e+q; lane loads 8B (4 halves).
__global__ __launch_bounds__(256) void k_gmm(
        const int* __restrict__ rowptr, const int* __restrict__ col,
        const float* __restrict__ dinv, const float* __restrict__ b,
        const __half* __restrict__ hw_in, const float* __restrict__ W,
        __half* __restrict__ hw_out) {
    __shared__ float sW[64 * 64];
    __shared__ float sA[4 * 64];
    int t = threadIdx.x;
    const float4* W4 = (const float4*)W;
    float4* sW4 = (float4*)sW;
    for (int i = t; i < 1024; i += 256) sW4[i] = W4[i];
    __syncthreads();

    int wave = t >> 6, lane = t & 63;
    int q = lane >> 4, sub = lane & 15;
    int i = blockIdx.x * 4 + wave;
    float di = dinv[i];
    int rs = rowptr[i], re = rowptr[i + 1];
    const uint2* hv = (const uint2*)hw_in;     // 4 halves per element; 16 per row
    float4 self4 = h4_to_f4(hv[i * 16 + sub]);
    float4 b4 = ((const float4*)b)[sub];

    float ax = 0.f, ay = 0.f, az = 0.f, aw = 0.f;
    float bx = 0.f, by = 0.f, bz = 0.f, bw = 0.f;
    int e = rs;
    for (; e + 16 <= re; e += 16) {
        int s0 = __builtin_nontemporal_load(&col[e + q]);
        int s1 = __builtin_nontemporal_load(&col[e + 4 + q]);
        int s2 = __builtin_nontemporal_load(&col[e + 8 + q]);
        int s3 = __builtin_nontemporal_load(&col[e + 12 + q]);
        uint2 u0 = hv[s0 * 16 + sub];
        uint2 u1 = hv[s1 * 16 + sub];
        uint2 u2 = hv[s2 * 16 + sub];
        uint2 u3 = hv[s3 * 16 + sub];
        float4 v0 = h4_to_f4(u0);
        float4 v1 = h4_to_f4(u1);
        float4 v2 = h4_to_f4(u2);
        float4 v3 = h4_to_f4(u3);
        ax += v0.x; ay += v0.y; az += v0.z; aw += v0.w;
        bx += v1.x; by += v1.y; bz += v1.z; bw += v1.w;
        ax += v2.x; ay += v2.y; az += v2.z; aw += v2.w;
        bx += v3.x; by += v3.y; bz += v3.z; bw += v3.w;
    }
    for (; e + 4 <= re; e += 4) {
        int s0 = col[e + q];
        float4 v0 = h4_to_f4(hv[s0 * 16 + sub]);
        ax += v0.x; ay += v0.y; az += v0.z; aw += v0.w;
    }
    if (e + q < re) {
        int s0 = col[e + q];
        float4 v0 = h4_to_f4(hv[s0 * 16 + sub]);
        bx += v0.x; by += v0.y; bz += v0.z; bw += v0.w;
    }
    ax += bx; ay += by; az += bz; aw += bw;
    ax += __shfl_xor(ax, 16); ay += __shfl_xor(ay, 16);
    az += __shfl_xor(az, 16); aw += __shfl_xor(aw, 16);
    ax += __shfl_xor(ax, 32); ay += __shfl_xor(ay, 32);
    az += __shfl_xor(az, 32); aw += __shfl_xor(aw, 32);

    float4 r;
    r.x = fmaxf(fmaf(di, ax + self4.x, b4.x), 0.f);
    r.y = fmaxf(fmaf(di, ay + self4.y, b4.y), 0.f);
    r.z = fmaxf(fmaf(di, az + self4.z, b4.z), 0.f);
    r.w = fmaxf(fmaf(di, aw + self4.w, b4.w), 0.f);
    if (q == 0) ((float4*)&sA[wave * 64])[sub] = r;

    const float4* sA4 = (const float4*)&sA[wave * 64];
    float sum = 0.f;
#pragma unroll
    for (int k4 = 0; k4 < 16; ++k4) {
        float4 a4 = sA4[k4];
        sum = fmaf(a4.x, sW[(k4 * 4 + 0) * 64 + lane], sum);
        sum = fmaf(a4.y, sW[(k4 * 4 + 1) * 64 + lane], sum);
        sum = fmaf(a4.z, sW[(k4 * 4 + 2) * 64 + lane], sum);
        sum = fmaf(a4.w, sW[(k4 * 4 + 3) * 64 + lane], sum);
    }
    hw_out[i * 64 + lane] = __float2half_rn(sum * di);
}

// ---------------- layer-3 gather (fp16 in, fp32 conv out) ----------------
__global__ __launch_bounds__(256) void k_gather3(
        const int* __restrict__ rowptr, const int* __restrict__ col,
        const float* __restrict__ dinv, const float* __restrict__ b,
        const __half* __restrict__ hw_in, float* __restrict__ conv) {
    int t = threadIdx.x;
    int wave = t >> 6, lane = t & 63;
    int q = lane >> 4, sub = lane & 15;
    int i = blockIdx.x * 4 + wave;
    float di = dinv[i];
    int rs = rowptr[i], re = rowptr[i + 1];
    const uint2* hv = (const uint2*)hw_in;
    float4 self4 = h4_to_f4(hv[i * 16 + sub]);
    float4 b4 = ((const float4*)b)[sub];

    float ax = 0.f, ay = 0.f, az = 0.f, aw = 0.f;
    float bx = 0.f, by = 0.f, bz = 0.f, bw = 0.f;
    int e = rs;
    for (; e + 16 <= re; e += 16) {
        int s0 = __builtin_nontemporal_load(&col[e + q]);
        int s1 = __builtin_nontemporal_load(&col[e + 4 + q]);
        int s2 = __builtin_nontemporal_load(&col[e + 8 + q]);
        int s3 = __builtin_nontemporal_load(&col[e + 12 + q]);
        float4 v0 = h4_to_f4(hv[s0 * 16 + sub]);
        float4 v1 = h4_to_f4(hv[s1 * 16 + sub]);
        float4 v2 = h4_to_f4(hv[s2 * 16 + sub]);
        float4 v3 = h4_to_f4(hv[s3 * 16 + sub]);
        ax += v0.x; ay += v0.y; az += v0.z; aw += v0.w;
        bx += v1.x; by += v1.y; bz += v1.z; bw += v1.w;
        ax += v2.x; ay += v2.y; az += v2.z; aw += v2.w;
        bx += v3.x; by += v3.y; bz += v3.z; bw += v3.w;
    }
    for (; e + 4 <= re; e += 4) {
        int s0 = col[e + q];
        float4 v0 = h4_to_f4(hv[s0 * 16 + sub]);
        ax += v0.x; ay += v0.y; az += v0.z; aw += v0.w;
    }
    if (e + q < re) {
        int s0 = col[e + q];
        float4 v0 = h4_to_f4(hv[s0 * 16 + sub]);
        bx += v0.x; by += v0.y; bz += v0.z; bw += v0.w;
    }
    ax += bx; ay += by; az += bz; aw += bw;
    ax += __shfl_xor(ax, 16); ay += __shfl_xor(ay, 16);
    az += __shfl_xor(az, 16); aw += __shfl_xor(aw, 16);
    ax += __shfl_xor(ax, 32); ay += __shfl_xor(ay, 32);
    az += __shfl_xor(az, 32); aw += __shfl_xor(aw, 32);

    if (q == 0) {
        float4 r;
        r.x = fmaf(di, ax + self4.x, b4.x);
        r.y = fmaf(di, ay + self4.y, b4.y);
        r.z = fmaf(di, az + self4.z, b4.z);
        r.w = fmaf(di, aw + self4.w, b4.w);
        ((float4*)&conv[i * 64])[sub] = r;
    }
}

// ---------------- segmented mean-pool ----------------
__global__ __launch_bounds__(256) void k_pool(
        const float* __restrict__ conv, const int* __restrict__ gstart,
        float* __restrict__ pooled) {
    int t = threadIdx.x;
    int wave = t >> 6, lane = t & 63;
    int g = blockIdx.x * 4 + wave;
    int n0 = gstart[g], n1 = gstart[g + 1];
    float acc = 0.f;
    for (int i = n0; i < n1; ++i) acc += conv[(size_t)i * 64 + lane];
    int n = n1 - n0;
    pooled[g * 64 + lane] = (n > 0) ? acc / (float)n : 0.f;
}

// ---------------- dense + softmax + threshold: 8 graphs per block ----------------
__global__ __launch_bounds__(256) void k_dense(
        const float* __restrict__ pooled, const float* __restrict__ Wd,
        const float* __restrict__ bd, float* __restrict__ out) {
    __shared__ float sp[8][64];
    __shared__ float red[8][4];
    int t = threadIdx.x;
    int g0 = blockIdx.x * 8;
    for (int idx = t; idx < 512; idx += 256) {
        int g = idx >> 6, k = idx & 63;
        sp[g][k] = pooled[(g0 + g) * 64 + k];
    }
    __syncthreads();

    float acc[8][8];
#pragma unroll
    for (int r = 0; r < 8; ++r) {
        float bv = bd[r * 256 + t];
#pragma unroll
        for (int g = 0; g < 8; ++g) acc[g][r] = bv;
    }
    for (int k = 0; k < 64; ++k) {
        float w[8];
#pragma unroll
        for (int r = 0; r < 8; ++r) w[r] = Wd[k * BIOPRINT + r * 256 + t];
#pragma unroll
        for (int g = 0; g < 8; ++g) {
            float h = sp[g][k];
#pragma unroll
            for (int r = 0; r < 8; ++r) acc[g][r] = fmaf(h, w[r], acc[g][r]);
        }
    }
    int wave = t >> 6, lane = t & 63;
    float gm[8];
#pragma unroll
    for (int g = 0; g < 8; ++g) {
        float m = acc[g][0];
#pragma unroll
        for (int r = 1; r < 8; ++r) m = fmaxf(m, acc[g][r]);
#pragma unroll
        for (int off = 32; off > 0; off >>= 1) m = fmaxf(m, __shfl_xor(m, off));
        if (lane == 0) red[g][wave] = m;
    }
    __syncthreads();
#pragma unroll
    for (int g = 0; g < 8; ++g)
        gm[g] = fmaxf(fmaxf(red[g][0], red[g][1]), fmaxf(red[g][2], red[g][3]));
    __syncthreads();
    float gs[8];
#pragma unroll
    for (int g = 0; g < 8; ++g) {
        float s = 0.f;
#pragma unroll
        for (int r = 0; r < 8; ++r) { acc[g][r] = expf(acc[g][r] - gm[g]); s += acc[g][r]; }
#pragma unroll
        for (int off = 32; off > 0; off >>= 1) s += __shfl_xor(s, off);
        if (lane == 0) red[g][wave] = s;
    }
    __syncthreads();
#pragma unroll
    for (int g = 0; g < 8; ++g)
        gs[g] = red[g][0] + red[g][1] + red[g][2] + red[g][3];
#pragma unroll
    for (int g = 0; g < 8; ++g)
#pragma unroll
        for (int r = 0; r < 8; ++r) {
            float p = acc[g][r] / gs[g];
            out[(size_t)(g0 + g) * BIOPRINT + r * 256 + t] = (p >= 0.5f) ? 1.0f : 0.0f;
        }
}

// ---------------- launch ----------------

extern "C" void kernel_launch(void* const* d_in, const int* in_sizes, int n_in,
                              void* d_out, int out_size, void* d_ws, size_t ws_size,
                              hipStream_t stream) {
    const float* x     = (const float*)d_in[0];
    const int*   ei    = (const int*)d_in[1];
    const int*   batch = (const int*)d_in[2];
    const float* W1 = (const float*)d_in[3];
    const float* b1 = (const float*)d_in[4];
    const float* W2 = (const float*)d_in[5];
    const float* b2 = (const float*)d_in[6];
    const float* W3 = (const float*)d_in[7];
    const float* b3 = (const float*)d_in[8];
    const float* Wd = (const float*)d_in[9];
    const float* bd = (const float*)d_in[10];
    float* out = (float*)d_out;

    const int* src = ei;
    const int* dst = ei + N_EDGES;

    char* ws = (char*)d_ws;
    size_t off = 0;
    auto alloc = [&](size_t bytes) {
        void* p = ws + off;
        off += (bytes + 255) & ~(size_t)255;
        return p;
    };
    int*    deg    = (int*)alloc(N_NODES * sizeof(int));
    float*  dinv   = (float*)alloc(N_NODES * sizeof(float));
    float*  pooled = (float*)alloc(N_GRAPHS * HIDDEN * sizeof(float));
    int*    rowptr = (int*)alloc((N_NODES + 1) * sizeof(int));
    int*    bsum   = (int*)alloc(N_SCAN_BLOCKS * sizeof(int));
    int*    cursor = (int*)alloc(N_NODES * sizeof(int));
    int*    gstart = (int*)alloc((N_GRAPHS + 1) * sizeof(int));
    int*    col    = (int*)alloc((size_t)N_EDGES * sizeof(int));
    __half* bufA   = (__half*)alloc((size_t)N_NODES * HIDDEN * sizeof(__half));
    __half* bufB   = (__half*)alloc((size_t)N_NODES * HIDDEN * sizeof(__half));
    float*  conv   = (float*)alloc((size_t)N_NODES * HIDDEN * sizeof(float));

    hipMemsetAsync(deg, 0, N_NODES * sizeof(int), stream);

    k_deg<<<(N_EDGES + 255) / 256, 256, 0, stream>>>(dst, deg, N_EDGES);
    k_dinv<<<(N_NODES + 255) / 256, 256, 0, stream>>>(deg, dinv, N_NODES);

    k_scan1<<<N_SCAN_BLOCKS, SCAN_BLK, 0, stream>>>(deg, rowptr, bsum, N_NODES);
    k_scan2<<<1, 64, 0, stream>>>(bsum, N_SCAN_BLOCKS);
    k_scan3<<<N_SCAN_BLOCKS, SCAN_BLK, 0, stream>>>(rowptr, deg, bsum, cursor, N_NODES);
    for (int p = 0; p < 4; ++p) {
        k_fillp<<<(N_EDGES + 255) / 256, 256, 0, stream>>>(
            src, dst, cursor, col, p * FILL_SLICE, (p + 1) * FILL_SLICE, N_EDGES);
    }
    k_gstart<<<5, 256, 0, stream>>>(batch, gstart);

    const int mm_grid = N_NODES / 4;          // 25000
    k_mm<<<mm_grid, 256, 0, stream>>>(x, W1, dinv, bufA);
    k_gmm<<<mm_grid, 256, 0, stream>>>(rowptr, col, dinv, b1, bufA, W2, bufB);
    k_gmm<<<mm_grid, 256, 0, stream>>>(rowptr, col, dinv, b2, bufB, W3, bufA);
    k_gather3<<<mm_grid, 256, 0, stream>>>(rowptr, col, dinv, b3, bufA, conv);
    k_pool<<<N_GRAPHS / 4, 256, 0, stream>>>(conv, gstart, pooled);
    k_dense<<<N_GRAPHS / 8, 256, 0, stream>>>(pooled, Wd, bd, out);
}

// Round 9
// 590.387 us; speedup vs baseline: 1.6922x; 1.0030x over previous
//
#include <hip/hip_runtime.h>
#include <hip/hip_fp16.h>
#include <math.h>

#define N_NODES   100000
#define N_EDGES   1600000
#define N_FEAT    64
#define HIDDEN    64
#define BIOPRINT  2048
#define N_GRAPHS  1024

#define SCAN_BLK  1024
#define N_SCAN_BLOCKS ((N_NODES + SCAN_BLK - 1) / SCAN_BLK)   // 98
#define FILL_SLICE 50000                                       // 2 passes

__device__ __forceinline__ __half2 shx_h2(__half2 v, int m) {
    int x = __shfl_xor(*(int*)&v, m);
    return *(__half2*)&x;
}

// ---------------- degree ----------------

__global__ void k_deg(const int* __restrict__ dst, int* __restrict__ deg, int n) {
    int i = blockIdx.x * blockDim.x + threadIdx.x;
    if (i < n) atomicAdd(&deg[__builtin_nontemporal_load(&dst[i])], 1);
}

// ---------------- CSR build: scan1 (+dinv), scan3 (+inline bsum scan, +gstart) ----------------

__global__ __launch_bounds__(SCAN_BLK) void k_scan1(
        const int* __restrict__ deg, int* __restrict__ incl,
        int* __restrict__ bsum, float* __restrict__ dinv, int n) {
    __shared__ int tmp[SCAN_BLK];
    int t = threadIdx.x;
    int i = blockIdx.x * SCAN_BLK + t;
    int v = (i < n) ? deg[i] : 0;
    if (i < n) dinv[i] = rsqrtf((float)v + 1.0f);
    tmp[t] = v;
    __syncthreads();
    for (int off = 1; off < SCAN_BLK; off <<= 1) {
        int u = (t >= off) ? tmp[t - off] : 0;
        __syncthreads();
        tmp[t] += u;
        __syncthreads();
    }
    if (i < n) incl[i] = tmp[t];
    if (t == SCAN_BLK - 1) bsum[blockIdx.x] = tmp[t];
}

// blocks 0..97: rowptr/cursor from incl + locally-scanned bsum.
// blocks 98..99: gstart binary search (batch sorted).
__global__ __launch_bounds__(SCAN_BLK) void k_scan3(
        int* __restrict__ rowptr, const int* __restrict__ deg,
        const int* __restrict__ bsum, int* __restrict__ cursor,
        const int* __restrict__ batch, int* __restrict__ gstart, int n) {
    int t = threadIdx.x;
    int bid = blockIdx.x;
    if (bid >= N_SCAN_BLOCKS) {
        int g = (bid - N_SCAN_BLOCKS) * SCAN_BLK + t;
        if (g > N_GRAPHS) return;
        if (g == N_GRAPHS) { gstart[g] = N_NODES; return; }
        int lo = 0, hi = N_NODES;
        while (lo < hi) { int mid = (lo + hi) >> 1; if (batch[mid] < g) lo = mid + 1; else hi = mid; }
        gstart[g] = lo;
        return;
    }
    __shared__ int sb[128];
    if (t < 128) sb[t] = (t < N_SCAN_BLOCKS) ? bsum[t] : 0;
    __syncthreads();
    for (int off = 1; off < 128; off <<= 1) {
        int u = (t >= off && t < 128) ? sb[t - off] : 0;
        __syncthreads();
        if (t < 128) sb[t] += u;
        __syncthreads();
    }
    int base = (bid == 0) ? 0 : sb[bid - 1];
    int i = bid * SCAN_BLK + t;
    if (i < n) {
        int ex = rowptr[i] - deg[i] + base;
        rowptr[i] = ex;
        cursor[i] = ex;
    }
    if (i == 0) rowptr[n] = N_EDGES;
}

// fill pass: range-filtered so the write slice stays L2-resident
__global__ void k_fillp(const int* __restrict__ src, const int* __restrict__ dst,
                        int* __restrict__ cursor, int* __restrict__ col,
                        int lo, int hi, int n) {
    int e = blockIdx.x * blockDim.x + threadIdx.x;
    if (e < n) {
        int d = __builtin_nontemporal_load(&dst[e]);
        if (d >= lo && d < hi) {
            int s = __builtin_nontemporal_load(&src[e]);
            int pos = atomicAdd(&cursor[d], 1);
            col[pos] = s;
        }
    }
}

// ---------------- layer-1 matmul: hw1' = fp16[(x @ W1) * dinv] ----------------
__global__ __launch_bounds__(256) void k_mm(
        const float* __restrict__ h, const float* __restrict__ W,
        const float* __restrict__ dinv, __half* __restrict__ hw) {
    __shared__ float sW[64 * 64];
    __shared__ float sH[4 * 64];
    int t = threadIdx.x;
    const float4* W4 = (const float4*)W;
    float4* sW4 = (float4*)sW;
    for (int i = t; i < 1024; i += 256) sW4[i] = W4[i];
    int row0 = blockIdx.x * 4;
    int r = t >> 6, j = t & 63;
    sH[r * 64 + j] = h[(row0 + r) * 64 + j];
    __syncthreads();
    int i = row0 + r;
    float sum = 0.0f;
#pragma unroll
    for (int k = 0; k < 64; ++k) sum = fmaf(sH[r * 64 + k], sW[k * 64 + j], sum);
    hw[i * 64 + j] = __float2half_rn(sum * dinv[i]);
}

// ---------------- gather core: 8 lanes/row, fp16 pk accumulate ----------------
// oct = lane>>3 (edge slot), sub = lane&7 (16B chunk of the 128B row).
// Returns 8 fp32 feature sums (chunk sub) valid on ALL lanes after reduce.
__device__ __forceinline__ void gather8(
        const int* __restrict__ col, const uint4* __restrict__ hv,
        int rs, int re, int oct, int sub, float f[8]) {
    __half2 a0 = __float2half2_rn(0.f), a1 = a0, a2 = a0, a3 = a0;
    __half2 c0 = a0, c1 = a0, c2 = a0, c3 = a0;
    int e = rs;
    for (; e + 16 <= re; e += 16) {
        int s0 = __builtin_nontemporal_load(&col[e + oct]);
        int s1 = __builtin_nontemporal_load(&col[e + 8 + oct]);
        uint4 u0 = hv[(size_t)s0 * 8 + sub];
        uint4 u1 = hv[(size_t)s1 * 8 + sub];
        a0 = __hadd2(a0, *(__half2*)&u0.x); a1 = __hadd2(a1, *(__half2*)&u0.y);
        a2 = __hadd2(a2, *(__half2*)&u0.z); a3 = __hadd2(a3, *(__half2*)&u0.w);
        c0 = __hadd2(c0, *(__half2*)&u1.x); c1 = __hadd2(c1, *(__half2*)&u1.y);
        c2 = __hadd2(c2, *(__half2*)&u1.z); c3 = __hadd2(c3, *(__half2*)&u1.w);
    }
    if (e + 8 <= re) {
        int s0 = __builtin_nontemporal_load(&col[e + oct]);
        uint4 u0 = hv[(size_t)s0 * 8 + sub];
        a0 = __hadd2(a0, *(__half2*)&u0.x); a1 = __hadd2(a1, *(__half2*)&u0.y);
        a2 = __hadd2(a2, *(__half2*)&u0.z); a3 = __hadd2(a3, *(__half2*)&u0.w);
        e += 8;
    }
    if (e + oct < re) {
        int s0 = col[e + oct];
        uint4 u0 = hv[(size_t)s0 * 8 + sub];
        c0 = __hadd2(c0, *(__half2*)&u0.x); c1 = __hadd2(c1, *(__half2*)&u0.y);
        c2 = __hadd2(c2, *(__half2*)&u0.z); c3 = __hadd2(c3, *(__half2*)&u0.w);
    }
    a0 = __hadd2(a0, c0); a1 = __hadd2(a1, c1);
    a2 = __hadd2(a2, c2); a3 = __hadd2(a3, c3);
#pragma unroll
    for (int st = 8; st <= 32; st <<= 1) {
        a0 = __hadd2(a0, shx_h2(a0, st));
        a1 = __hadd2(a1, shx_h2(a1, st));
        a2 = __hadd2(a2, shx_h2(a2, st));
        a3 = __hadd2(a3, shx_h2(a3, st));
    }
    float2 f0 = __half22float2(a0), f1 = __half22float2(a1);
    float2 f2 = __half22float2(a2), f3 = __half22float2(a3);
    f[0] = f0.x; f[1] = f0.y; f[2] = f1.x; f[3] = f1.y;
    f[4] = f2.x; f[5] = f2.y; f[6] = f3.x; f[7] = f3.y;
}

// ---------------- fused gather(fp16) + relu + next matmul ----------------
__global__ __launch_bounds__(256) void k_gmm(
        const int* __restrict__ rowptr, const int* __restrict__ col,
        const float* __restrict__ dinv, const float* __restrict__ b,
        const __half* __restrict__ hw_in, const float* __restrict__ W,
        __half* __restrict__ hw_out) {
    __shared__ float sW[64 * 64];
    __shared__ float sA[4 * 64];
    int t = threadIdx.x;
    const float4* W4 = (const float4*)W;
    float4* sW4 = (float4*)sW;
    for (int i = t; i < 1024; i += 256) sW4[i] = W4[i];
    __syncthreads();

    int wave = t >> 6, lane = t & 63;
    int oct = lane >> 3, sub = lane & 7;
    int i = blockIdx.x * 4 + wave;
    float di = dinv[i];
    int rs = rowptr[i], re = rowptr[i + 1];
    const uint4* hv = (const uint4*)hw_in;

    float f[8];
    gather8(col, hv, rs, re, oct, sub, f);

    if (oct == 0) {
        uint4 us = hv[(size_t)i * 8 + sub];
        float2 s0 = __half22float2(*(__half2*)&us.x);
        float2 s1 = __half22float2(*(__half2*)&us.y);
        float2 s2 = __half22float2(*(__half2*)&us.z);
        float2 s3 = __half22float2(*(__half2*)&us.w);
        float sf[8] = {s0.x, s0.y, s1.x, s1.y, s2.x, s2.y, s3.x, s3.y};
        float4 ba = ((const float4*)b)[sub * 2];
        float4 bb = ((const float4*)b)[sub * 2 + 1];
        float bf[8] = {ba.x, ba.y, ba.z, ba.w, bb.x, bb.y, bb.z, bb.w};
        float r[8];
#pragma unroll
        for (int k = 0; k < 8; ++k) r[k] = fmaxf(fmaf(di, f[k] + sf[k], bf[k]), 0.f);
        *(float4*)&sA[wave * 64 + sub * 8]     = make_float4(r[0], r[1], r[2], r[3]);
        *(float4*)&sA[wave * 64 + sub * 8 + 4] = make_float4(r[4], r[5], r[6], r[7]);
    }

    // per-wave mm (same-wave LDS ordering)
    const float4* sA4 = (const float4*)&sA[wave * 64];
    float sum = 0.f;
#pragma unroll
    for (int k4 = 0; k4 < 16; ++k4) {
        float4 a4 = sA4[k4];
        sum = fmaf(a4.x, sW[(k4 * 4 + 0) * 64 + lane], sum);
        sum = fmaf(a4.y, sW[(k4 * 4 + 1) * 64 + lane], sum);
        sum = fmaf(a4.z, sW[(k4 * 4 + 2) * 64 + lane], sum);
        sum = fmaf(a4.w, sW[(k4 * 4 + 3) * 64 + lane], sum);
    }
    hw_out[(size_t)i * 64 + lane] = __float2half_rn(sum * di);
}

// ---------------- layer-3 gather (fp16 in, fp32 conv out) ----------------
__global__ __launch_bounds__(256) void k_gather3(
        const int* __restrict__ rowptr, const int* __restrict__ col,
        const float* __restrict__ dinv, const float* __restrict__ b,
        const __half* __restrict__ hw_in, float* __restrict__ conv) {
    int t = threadIdx.x;
    int wave = t >> 6, lane = t & 63;
    int oct = lane >> 3, sub = lane & 7;
    int i = blockIdx.x * 4 + wave;
    float di = dinv[i];
    int rs = rowptr[i], re = rowptr[i + 1];
    const uint4* hv = (const uint4*)hw_in;

    float f[8];
    gather8(col, hv, rs, re, oct, sub, f);

    if (oct == 0) {
        uint4 us = hv[(size_t)i * 8 + sub];
        float2 s0 = __half22float2(*(__half2*)&us.x);
        float2 s1 = __half22float2(*(__half2*)&us.y);
        float2 s2 = __half22float2(*(__half2*)&us.z);
        float2 s3 = __half22float2(*(__half2*)&us.w);
        float sf[8] = {s0.x, s0.y, s1.x, s1.y, s2.x, s2.y, s3.x, s3.y};
        float4 ba = ((const float4*)b)[sub * 2];
        float4 bb = ((const float4*)b)[sub * 2 + 1];
        float bf[8] = {ba.x, ba.y, ba.z, ba.w, bb.x, bb.y, bb.z, bb.w};
        float r[8];
#pragma unroll
        for (int k = 0; k < 8; ++k) r[k] = fmaf(di, f[k] + sf[k], bf[k]);
        *(float4*)&conv[(size_t)i * 64 + sub * 8]     = make_float4(r[0], r[1], r[2], r[3]);
        *(float4*)&conv[(size_t)i * 64 + sub * 8 + 4] = make_float4(r[4], r[5], r[6], r[7]);
    }
}

// ---------------- segmented mean-pool ----------------
__global__ __launch_bounds__(256) void k_pool(
        const float* __restrict__ conv, const int* __restrict__ gstart,
        float* __restrict__ pooled) {
    int t = threadIdx.x;
    int wave = t >> 6, lane = t & 63;
    int g = blockIdx.x * 4 + wave;
    int n0 = gstart[g], n1 = gstart[g + 1];
    float acc = 0.f;
    for (int i = n0; i < n1; ++i) acc += conv[(size_t)i * 64 + lane];
    int n = n1 - n0;
    pooled[g * 64 + lane] = (n > 0) ? acc / (float)n : 0.f;
}

// ---------------- dense + softmax + threshold: 8 graphs per block ----------------
__global__ __launch_bounds__(256) void k_dense(
        const float* __restrict__ pooled, const float* __restrict__ Wd,
        const float* __restrict__ bd, float* __restrict__ out) {
    __shared__ float sp[8][64];
    __shared__ float red[8][4];
    int t = threadIdx.x;
    int g0 = blockIdx.x * 8;
    for (int idx = t; idx < 512; idx += 256) {
        int g = idx >> 6, k = idx & 63;
        sp[g][k] = pooled[(g0 + g) * 64 + k];
    }
    __syncthreads();

    float acc[8][8];
#pragma unroll
    for (int r = 0; r < 8; ++r) {
        float bv = bd[r * 256 + t];
#pragma unroll
        for (int g = 0; g < 8; ++g) acc[g][r] = bv;
    }
    for (int k = 0; k < 64; ++k) {
        float w[8];
#pragma unroll
        for (int r = 0; r < 8; ++r) w[r] = Wd[k * BIOPRINT + r * 256 + t];
#pragma unroll
        for (int g = 0; g < 8; ++g) {
            float h = sp[g][k];
#pragma unroll
            for (int r = 0; r < 8; ++r) acc[g][r] = fmaf(h, w[r], acc[g][r]);
        }
    }
    int wave = t >> 6, lane = t & 63;
    float gm[8];
#pragma unroll
    for (int g = 0; g < 8; ++g) {
        float m = acc[g][0];
#pragma unroll
        for (int r = 1; r < 8; ++r) m = fmaxf(m, acc[g][r]);
#pragma unroll
        for (int off = 32; off > 0; off >>= 1) m = fmaxf(m, __shfl_xor(m, off));
        if (lane == 0) red[g][wave] = m;
    }
    __syncthreads();
#pragma unroll
    for (int g = 0; g < 8; ++g)
        gm[g] = fmaxf(fmaxf(red[g][0], red[g][1]), fmaxf(red[g][2], red[g][3]));
    __syncthreads();
    float gs[8];
#pragma unroll
    for (int g = 0; g < 8; ++g) {
        float s = 0.f;
#pragma unroll
        for (int r = 0; r < 8; ++r) { acc[g][r] = expf(acc[g][r] - gm[g]); s += acc[g][r]; }
#pragma unroll
        for (int off = 32; off > 0; off >>= 1) s += __shfl_xor(s, off);
        if (lane == 0) red[g][wave] = s;
    }
    __syncthreads();
#pragma unroll
    for (int g = 0; g < 8; ++g)
        gs[g] = red[g][0] + red[g][1] + red[g][2] + red[g][3];
#pragma unroll
    for (int g = 0; g < 8; ++g)
#pragma unroll
        for (int r = 0; r < 8; ++r) {
            float p = acc[g][r] / gs[g];
            out[(size_t)(g0 + g) * BIOPRINT + r * 256 + t] = (p >= 0.5f) ? 1.0f : 0.0f;
        }
}

// ---------------- launch ----------------

extern "C" void kernel_launch(void* const* d_in, const int* in_sizes, int n_in,
                              void* d_out, int out_size, void* d_ws, size_t ws_size,
                              hipStream_t stream) {
    const float* x     = (const float*)d_in[0];
    const int*   ei    = (const int*)d_in[1];
    const int*   batch = (const int*)d_in[2];
    const float* W1 = (const float*)d_in[3];
    const float* b1 = (const float*)d_in[4];
    const float* W2 = (const float*)d_in[5];
    const float* b2 = (const float*)d_in[6];
    const float* W3 = (const float*)d_in[7];
    const float* b3 = (const float*)d_in[8];
    const float* Wd = (const float*)d_in[9];
    const float* bd = (const float*)d_in[10];
    float* out = (float*)d_out;

    const int* src = ei;
    const int* dst = ei + N_EDGES;

    char* ws = (char*)d_ws;
    size_t off = 0;
    auto alloc = [&](size_t bytes) {
        void* p = ws + off;
        off += (bytes + 255) & ~(size_t)255;
        return p;
    };
    int*    deg    = (int*)alloc(N_NODES * sizeof(int));
    float*  dinv   = (float*)alloc(N_NODES * sizeof(float));
    float*  pooled = (float*)alloc(N_GRAPHS * HIDDEN * sizeof(float));
    int*    rowptr = (int*)alloc((N_NODES + 1) * sizeof(int));
    int*    bsum   = (int*)alloc(128 * sizeof(int));
    int*    cursor = (int*)alloc(N_NODES * sizeof(int));
    int*    gstart = (int*)alloc((N_GRAPHS + 1) * sizeof(int));
    int*    col    = (int*)alloc((size_t)N_EDGES * sizeof(int));
    __half* bufA   = (__half*)alloc((size_t)N_NODES * HIDDEN * sizeof(__half));
    __half* bufB   = (__half*)alloc((size_t)N_NODES * HIDDEN * sizeof(__half));
    float*  conv   = (float*)alloc((size_t)N_NODES * HIDDEN * sizeof(float));

    hipMemsetAsync(deg, 0, N_NODES * sizeof(int), stream);

    k_deg<<<(N_EDGES + 255) / 256, 256, 0, stream>>>(dst, deg, N_EDGES);
    k_scan1<<<N_SCAN_BLOCKS, SCAN_BLK, 0, stream>>>(deg, rowptr, bsum, dinv, N_NODES);
    k_scan3<<<N_SCAN_BLOCKS + 2, SCAN_BLK, 0, stream>>>(rowptr, deg, bsum, cursor,
                                                        batch, gstart, N_NODES);
    for (int p = 0; p < 2; ++p) {
        k_fillp<<<(N_EDGES + 255) / 256, 256, 0, stream>>>(
            src, dst, cursor, col, p * FILL_SLICE, (p + 1) * FILL_SLICE, N_EDGES);
    }

    const int mm_grid = N_NODES / 4;          // 25000
    k_mm<<<mm_grid, 256, 0, stream>>>(x, W1, dinv, bufA);
    k_gmm<<<mm_grid, 256, 0, stream>>>(rowptr, col, dinv, b1, bufA, W2, bufB);
    k_gmm<<<mm_grid, 256, 0, stream>>>(rowptr, col, dinv, b2, bufB, W3, bufA);
    k_gather3<<<mm_grid, 256, 0, stream>>>(rowptr, col, dinv, b3, bufA, conv);
    k_pool<<<N_GRAPHS / 4, 256, 0, stream>>>(conv, gstart, pooled);
    k_dense<<<N_GRAPHS / 8, 256, 0, stream>>>(pooled, Wd, bd, out);
}